// Round 8
// baseline (70.199 us; speedup 1.0000x reference)
//
#include <hip/hip_runtime.h>
#include <hip/hip_bf16.h>

// Problem constants (reference: K=512, D=128, N=8192)
#define KC 512
#define DD 128
#define NP 8192

// ws layout (bytes):
//   [0,      2KB)    sumc2    (512 f32)
//   [4096,   266240) CkT      (128 x 512 f32)
//   [266240, 299008) idx      (8192 i32)
//   [299008, 331776) rank2    (8192 i32)
//   [331776, 462848) cnts2    (512 x 64 i32)
//   [462848, 593920) offsflat (512 x 64 i32)
//   [593920, 659456) sorted   (8192 int2)
//   [659456, 663552) bcid     (512 x 2 i32)   boundary-partial cluster tags
//   [663552, 1187840) bpart   (512 x 2 x 128 f32) boundary partials

// ---------------- prep: transpose, sumc2, zero cnts2 ----------------
__global__ __launch_bounds__(256) void kprep(const float* __restrict__ Ck,
                                             float* __restrict__ CkT,
                                             float* __restrict__ sumc2,
                                             int* __restrict__ cnts2) {
    const int b = blockIdx.x;
    const int t = threadIdx.x;
    if (b < 64) {
        const float4 v = *(const float4*)(Ck + b * 1024 + t * 4);
        const int k = b * 8 + (t >> 5);
        const int d = (t & 31) * 4;
        CkT[(d + 0) * KC + k] = v.x;
        CkT[(d + 1) * KC + k] = v.y;
        CkT[(d + 2) * KC + k] = v.z;
        CkT[(d + 3) * KC + k] = v.w;
    } else if (b == 64) {
        #pragma unroll
        for (int c = 0; c < 2; ++c) {
            const int k = t + c * 256;
            const float4* row = (const float4*)(Ck + k * DD);
            float s = 0.f;
            #pragma unroll
            for (int i = 0; i < 32; ++i) {
                const float4 v = row[i];
                s += v.x * v.x + v.y * v.y + v.z * v.z + v.w * v.w;
            }
            sumc2[k] = s;
        }
    } else {
        int* dst = cnts2 + (b - 65) * 2048;
        #pragma unroll
        for (int i = 0; i < 8; ++i) dst[t + 256 * i] = 0;
    }
}

// ---------------- assign: distances + argmin -> idx[p], rank2[p] ----------------
// 1024 blocks x 128 thr (2 waves). Block: 8 points; wave h owns centroid half h;
// lane owns 4 cents (contiguous 16B in CkT row -> coalesced dwordx4 from L2,
// reg-staged, no loop barriers). Single ascending-d fmaf chain (absmax 4e-3).
__global__ __launch_bounds__(128) void kassign(const float* __restrict__ X,
                                               const float* __restrict__ CkT,
                                               const float* __restrict__ sumc2,
                                               int* __restrict__ idxout,
                                               int* __restrict__ rank2,
                                               int* __restrict__ cnts2) {
    __shared__ __align__(16) float xs[8 * DD];   // 4 KB
    __shared__ float bvx[2][8];
    __shared__ int   bix[2][8];

    const int tid  = threadIdx.x;
    const int lane = tid & 63;
    const int h    = tid >> 6;
    const int p0   = blockIdx.x * 8;

    {
        const float4* Xv = (const float4*)(X + p0 * DD);
        float4* xv = (float4*)xs;
        xv[tid]       = Xv[tid];
        xv[tid + 128] = Xv[tid + 128];
    }
    __syncthreads();

    const float* cp = CkT + h * 256 + 4 * lane;  // this thread's 4-cent column

    float4 cn[4], cc[4];
    #pragma unroll
    for (int dd = 0; dd < 4; ++dd) cn[dd] = *(const float4*)(cp + dd * KC);

    float acc[8][4];
    #pragma unroll
    for (int p = 0; p < 8; ++p)
        #pragma unroll
        for (int j = 0; j < 4; ++j) acc[p][j] = 0.f;

    #pragma unroll 4
    for (int t = 0; t < 32; ++t) {
        #pragma unroll
        for (int dd = 0; dd < 4; ++dd) cc[dd] = cn[dd];
        if (t < 31) {
            #pragma unroll
            for (int dd = 0; dd < 4; ++dd)
                cn[dd] = *(const float4*)(cp + ((t + 1) * 4 + dd) * KC);
        }
        float4 xf[8];
        #pragma unroll
        for (int p = 0; p < 8; ++p)
            xf[p] = *(const float4*)&xs[p * DD + t * 4];   // uniform -> LDS broadcast
        #pragma unroll
        for (int dd = 0; dd < 4; ++dd) {
            #pragma unroll
            for (int p = 0; p < 8; ++p) {
                const float xv = (&xf[p].x)[dd];
                acc[p][0] = fmaf(xv, cc[dd].x, acc[p][0]);
                acc[p][1] = fmaf(xv, cc[dd].y, acc[p][1]);
                acc[p][2] = fmaf(xv, cc[dd].z, acc[p][2]);
                acc[p][3] = fmaf(xv, cc[dd].w, acc[p][3]);
            }
        }
    }

    // per-thread argmin over its 4 centroids (ascending index, strict <)
    float bestv[8];
    int   besti[8];
    #pragma unroll
    for (int p = 0; p < 8; ++p) { bestv[p] = 3.4e38f; besti[p] = 0; }
    const float4 s2v = *(const float4*)(sumc2 + h * 256 + 4 * lane);
    #pragma unroll
    for (int j = 0; j < 4; ++j) {
        const int cent = h * 256 + 4 * lane + j;
        const float s2 = (&s2v.x)[j];
        #pragma unroll
        for (int p = 0; p < 8; ++p) {
            const float v = fmaf(-2.f, acc[p][j], s2);   // monotonic proxy for d2
            if (v < bestv[p]) { bestv[p] = v; besti[p] = cent; }
        }
    }
    // wave butterfly, tie-break on smaller index (jnp.argmin = first min)
    #pragma unroll
    for (int off = 1; off < 64; off <<= 1) {
        #pragma unroll
        for (int p = 0; p < 8; ++p) {
            const float ov = __shfl_xor(bestv[p], off);
            const int   oi = __shfl_xor(besti[p], off);
            if (ov < bestv[p] || (ov == bestv[p] && oi < besti[p])) {
                bestv[p] = ov; besti[p] = oi;
            }
        }
    }
    if (lane == 0) {
        #pragma unroll
        for (int p = 0; p < 8; ++p) { bvx[h][p] = bestv[p]; bix[h][p] = besti[p]; }
    }
    __syncthreads();
    if (tid < 8) {
        const float v0 = bvx[0][tid], v1 = bvx[1][tid];
        const int c = (v1 < v0) ? bix[1][tid] : bix[0][tid];  // tie -> lower idx
        const int p = p0 + tid;
        idxout[p] = c;
        rank2[p] = atomicAdd(&cnts2[c * 64 + (blockIdx.x & 63)], 1);
    }
}

// ---------------- scan + scatter (1 block x 1024) ----------------
__global__ __launch_bounds__(1024) void kscan(const int* __restrict__ cnts2,
                                              const int* __restrict__ idx,
                                              const int* __restrict__ rank2,
                                              int* __restrict__ offsflat,
                                              int2* __restrict__ sorted,
                                              float* __restrict__ out) {
    __shared__ int sex[1024];
    const int t = threadIdx.x;

    int arr[32];
    {
        const int4* src = (const int4*)cnts2 + t * 8;
        #pragma unroll
        for (int i = 0; i < 8; ++i) {
            const int4 v = src[i];
            arr[4 * i + 0] = v.x; arr[4 * i + 1] = v.y;
            arr[4 * i + 2] = v.z; arr[4 * i + 3] = v.w;
        }
    }
    int loc[32];
    int tot = 0;
    #pragma unroll
    for (int i = 0; i < 32; ++i) { loc[i] = tot; tot += arr[i]; }

    sex[t] = tot;
    __syncthreads();
    for (int off = 1; off < 1024; off <<= 1) {
        const int a = (t >= off) ? sex[t - off] : 0;
        __syncthreads();
        sex[t] += a;
        __syncthreads();
    }
    const int excl = sex[t] - tot;

    {
        int4* dst = (int4*)offsflat + t * 8;
        #pragma unroll
        for (int i = 0; i < 8; ++i)
            dst[i] = make_int4(excl + loc[4 * i + 0], excl + loc[4 * i + 1],
                               excl + loc[4 * i + 2], excl + loc[4 * i + 3]);
    }

    __syncthreads();
    sex[t] = excl;
    __syncthreads();
    if (t < 512) {
        const int start = sex[2 * t];
        const int end   = (t == 511) ? NP : sex[2 * t + 2];
        out[KC * DD + t] = (float)(end - start);     // nItems
    }

    __syncthreads();
    #pragma unroll
    for (int i = 0; i < 8; ++i) {
        const int p = t + 1024 * i;
        const int c = idx[p];
        const int g = (p >> 3) & 63;
        const int s0 = offsflat[c * 64 + g] + rank2[p];
        sorted[s0] = make_int2(p, c);
    }
}

// ---------------- gather: 16 slots/block, NO global atomics ----------------
// Interior runs (start>0 && end<15): this block is the exclusive owner of that
// cluster -> plain store to out. Boundary runs (touch slot 0 or 15): write the
// partial to bpart[b][0/1] with cluster tag bcid[b][0/1]; kreduce sums them.
__global__ __launch_bounds__(128) void kgather(const float* __restrict__ X,
                                               const int2* __restrict__ sorted,
                                               float* __restrict__ out,
                                               float* __restrict__ bpart,
                                               int* __restrict__ bcid) {
    const int d = threadIdx.x;
    const int b = blockIdx.x;
    const int s0 = b * 16;

    int2 pc[16];
    #pragma unroll
    for (int i = 0; i < 16; ++i) pc[i] = sorted[s0 + i];

    float xr[16];
    #pragma unroll
    for (int i = 0; i < 16; ++i) xr[i] = X[pc[i].x * DD + d];

    float sum = xr[0];
    int runstart = 0;
    #pragma unroll
    for (int i = 1; i < 16; ++i) {
        if (pc[i].y != pc[i - 1].y) {               // block-uniform branch
            if (runstart == 0) {                    // prefix partial
                bpart[(b * 2 + 0) * DD + d] = sum;
                if (d == 0) bcid[b * 2 + 0] = pc[runstart].y;
            } else {                                // interior run: exclusive owner
                out[pc[runstart].y * DD + d] = sum;
            }
            sum = 0.f;
            runstart = i;
        }
        sum += xr[i];
    }
    if (runstart == 0) {                            // whole block = one run
        bpart[(b * 2 + 0) * DD + d] = sum;
        if (d == 0) { bcid[b * 2 + 0] = pc[0].y; bcid[b * 2 + 1] = -1; }
    } else {                                        // suffix partial
        bpart[(b * 2 + 1) * DD + d] = sum;
        if (d == 0) bcid[b * 2 + 1] = pc[runstart].y;
    }
}

// ---------------- reduce: one block per cluster, sums tagged partials ----------------
__global__ __launch_bounds__(128) void kreduce(const int* __restrict__ offsflat,
                                               const float* __restrict__ bpart,
                                               const int* __restrict__ bcid,
                                               float* __restrict__ out) {
    const int c = blockIdx.x;
    const int d = threadIdx.x;
    const int s  = offsflat[c * 64];
    const int e_ = (c == KC - 1) ? NP : offsflat[(c + 1) * 64];
    const int cnt = e_ - s;
    if (cnt == 0) { out[c * DD + d] = 0.f; return; }
    const int e  = e_ - 1;
    const int b0 = s >> 4, b1 = e >> 4;
    if (b0 == b1 && (s & 15) != 0 && (e & 15) != 15) return;   // interior-stored by kgather
    float sum = 0.f;
    for (int b = b0; b <= b1; ++b) {                // ascending: deterministic order
        if (bcid[2 * b + 0] == c) sum += bpart[(2 * b + 0) * DD + d];
        if (bcid[2 * b + 1] == c) sum += bpart[(2 * b + 1) * DD + d];
    }
    out[c * DD + d] = sum;
}

extern "C" void kernel_launch(void* const* d_in, const int* in_sizes, int n_in,
                              void* d_out, int out_size, void* d_ws, size_t ws_size,
                              hipStream_t stream) {
    const float* locF = (const float*)d_in[0];
    const float* Ck   = (const float*)d_in[1];
    float* out      = (float*)d_out;
    char*  ws       = (char*)d_ws;
    float* sumc2    = (float*)(ws);
    float* CkT      = (float*)(ws + 4096);
    int*   idx      = (int*)(ws + 266240);
    int*   rank2    = (int*)(ws + 299008);
    int*   cnts2    = (int*)(ws + 331776);
    int*   offsflat = (int*)(ws + 462848);
    int2*  sorted   = (int2*)(ws + 593920);
    int*   bcid     = (int*)(ws + 659456);
    float* bpart    = (float*)(ws + 663552);

    hipLaunchKernelGGL(kprep,   dim3(81),   dim3(256),  0, stream, Ck, CkT, sumc2, cnts2);
    hipLaunchKernelGGL(kassign, dim3(1024), dim3(128),  0, stream, locF, CkT, sumc2, idx, rank2, cnts2);
    hipLaunchKernelGGL(kscan,   dim3(1),    dim3(1024), 0, stream, cnts2, idx, rank2, offsflat, sorted, out);
    hipLaunchKernelGGL(kgather, dim3(512),  dim3(128),  0, stream, locF, sorted, out, bpart, bcid);
    hipLaunchKernelGGL(kreduce, dim3(512),  dim3(128),  0, stream, offsflat, bpart, bcid, out);
}

// Round 9
// 56.858 us; speedup vs baseline: 1.2346x; 1.2346x over previous
//
#include <hip/hip_runtime.h>
#include <hip/hip_bf16.h>

// Problem constants (reference: K=512, D=128, N=8192)
#define KC 512
#define DD 128
#define NP 8192

// ws layout (bytes):
//   [0,      2KB)    sumc2 (512 f32)
//   [4096,   266240) CkT   (128 x 512 f32)
//   [266240, 299008) idx   (8192 i32)
//   [299008, 430080) cnts2 (512 x 64 i32) split counters
//   [430080, +16MB)  part  (64 groups x 512 c x 128 d f32)

// ---------------- prep: transpose, sumc2, zero cnts2 ----------------
__global__ __launch_bounds__(256) void kprep(const float* __restrict__ Ck,
                                             float* __restrict__ CkT,
                                             float* __restrict__ sumc2,
                                             int* __restrict__ cnts2) {
    const int b = blockIdx.x;
    const int t = threadIdx.x;
    if (b < 64) {
        const float4 v = *(const float4*)(Ck + b * 1024 + t * 4);
        const int k = b * 8 + (t >> 5);
        const int d = (t & 31) * 4;
        CkT[(d + 0) * KC + k] = v.x;
        CkT[(d + 1) * KC + k] = v.y;
        CkT[(d + 2) * KC + k] = v.z;
        CkT[(d + 3) * KC + k] = v.w;
    } else if (b == 64) {
        #pragma unroll
        for (int c = 0; c < 2; ++c) {
            const int k = t + c * 256;
            const float4* row = (const float4*)(Ck + k * DD);
            float s = 0.f;
            #pragma unroll
            for (int i = 0; i < 32; ++i) {
                const float4 v = row[i];
                s += v.x * v.x + v.y * v.y + v.z * v.z + v.w * v.w;
            }
            sumc2[k] = s;
        }
    } else {
        int* dst = cnts2 + (b - 65) * 2048;
        #pragma unroll
        for (int i = 0; i < 8; ++i) dst[t + 256 * i] = 0;
    }
}

// ---------------- assign: distances + argmin -> idx[p] + split counts ----------------
// 1024 blocks x 128 thr (2 waves). Block: 8 points; wave h owns centroid half h;
// lane owns 4 cents (contiguous 16B in CkT row -> coalesced dwordx4 from L2,
// reg-staged, no loop barriers). Single ascending-d fmaf chain (absmax 4e-3).
__global__ __launch_bounds__(128) void kassign(const float* __restrict__ X,
                                               const float* __restrict__ CkT,
                                               const float* __restrict__ sumc2,
                                               int* __restrict__ idxout,
                                               int* __restrict__ cnts2) {
    __shared__ __align__(16) float xs[8 * DD];   // 4 KB
    __shared__ float bvx[2][8];
    __shared__ int   bix[2][8];

    const int tid  = threadIdx.x;
    const int lane = tid & 63;
    const int h    = tid >> 6;
    const int p0   = blockIdx.x * 8;

    {
        const float4* Xv = (const float4*)(X + p0 * DD);
        float4* xv = (float4*)xs;
        xv[tid]       = Xv[tid];
        xv[tid + 128] = Xv[tid + 128];
    }
    __syncthreads();

    const float* cp = CkT + h * 256 + 4 * lane;  // this thread's 4-cent column

    float4 cn[4], cc[4];
    #pragma unroll
    for (int dd = 0; dd < 4; ++dd) cn[dd] = *(const float4*)(cp + dd * KC);

    float acc[8][4];
    #pragma unroll
    for (int p = 0; p < 8; ++p)
        #pragma unroll
        for (int j = 0; j < 4; ++j) acc[p][j] = 0.f;

    #pragma unroll 4
    for (int t = 0; t < 32; ++t) {
        #pragma unroll
        for (int dd = 0; dd < 4; ++dd) cc[dd] = cn[dd];
        if (t < 31) {
            #pragma unroll
            for (int dd = 0; dd < 4; ++dd)
                cn[dd] = *(const float4*)(cp + ((t + 1) * 4 + dd) * KC);
        }
        float4 xf[8];
        #pragma unroll
        for (int p = 0; p < 8; ++p)
            xf[p] = *(const float4*)&xs[p * DD + t * 4];   // uniform -> LDS broadcast
        #pragma unroll
        for (int dd = 0; dd < 4; ++dd) {
            #pragma unroll
            for (int p = 0; p < 8; ++p) {
                const float xv = (&xf[p].x)[dd];
                acc[p][0] = fmaf(xv, cc[dd].x, acc[p][0]);
                acc[p][1] = fmaf(xv, cc[dd].y, acc[p][1]);
                acc[p][2] = fmaf(xv, cc[dd].z, acc[p][2]);
                acc[p][3] = fmaf(xv, cc[dd].w, acc[p][3]);
            }
        }
    }

    // per-thread argmin over its 4 centroids (ascending index, strict <)
    float bestv[8];
    int   besti[8];
    #pragma unroll
    for (int p = 0; p < 8; ++p) { bestv[p] = 3.4e38f; besti[p] = 0; }
    const float4 s2v = *(const float4*)(sumc2 + h * 256 + 4 * lane);
    #pragma unroll
    for (int j = 0; j < 4; ++j) {
        const int cent = h * 256 + 4 * lane + j;
        const float s2 = (&s2v.x)[j];
        #pragma unroll
        for (int p = 0; p < 8; ++p) {
            const float v = fmaf(-2.f, acc[p][j], s2);   // monotonic proxy for d2
            if (v < bestv[p]) { bestv[p] = v; besti[p] = cent; }
        }
    }
    // wave butterfly, tie-break on smaller index (jnp.argmin = first min)
    #pragma unroll
    for (int off = 1; off < 64; off <<= 1) {
        #pragma unroll
        for (int p = 0; p < 8; ++p) {
            const float ov = __shfl_xor(bestv[p], off);
            const int   oi = __shfl_xor(besti[p], off);
            if (ov < bestv[p] || (ov == bestv[p] && oi < besti[p])) {
                bestv[p] = ov; besti[p] = oi;
            }
        }
    }
    if (lane == 0) {
        #pragma unroll
        for (int p = 0; p < 8; ++p) { bvx[h][p] = bestv[p]; bix[h][p] = besti[p]; }
    }
    __syncthreads();
    if (tid < 8) {
        const float v0 = bvx[0][tid], v1 = bvx[1][tid];
        const int c = (v1 < v0) ? bix[1][tid] : bix[0][tid];  // tie -> lower idx
        idxout[p0 + tid] = c;
        atomicAdd(&cnts2[c * 64 + (blockIdx.x & 63)], 1);     // <=32 contention/addr
    }
}

// ---------------- hist: LDS partial sums, fixed work per block ----------------
// 256 blocks x 256 thr: g = b>>2 (128-point group), h = (b>>1)&1 (dim half),
// ch = b&1 (cluster half). LDS tile [256 c][64 d] = 64 KB. Wave w owns points
// w*32..w*32+31; lane = local dim. ds_add lanes hit distinct d -> 2-way bank
// aliasing only (free, m136); hot cluster = same-row adds, <=31 collisions.
// Work per block is FIXED regardless of cluster skew.
__global__ __launch_bounds__(256) void khist(const float* __restrict__ X,
                                             const int* __restrict__ idx,
                                             float* __restrict__ part) {
    __shared__ float lds[256 * 64];   // 64 KB
    __shared__ int sidx[128];
    const int b = blockIdx.x;
    const int g = b >> 2, h = (b >> 1) & 1, ch = b & 1;
    const int t = threadIdx.x;
    const int lane = t & 63;
    const int w = t >> 6;

    {
        float4* lz = (float4*)lds;
        const float4 z = make_float4(0.f, 0.f, 0.f, 0.f);
        #pragma unroll
        for (int i = 0; i < 16; ++i) lz[t + 256 * i] = z;
    }
    if (t < 128) sidx[t] = idx[g * 128 + t];
    __syncthreads();

    const int clo = ch * 256;
    const float* Xh = X + (size_t)g * 128 * DD + h * 64 + lane;
    #pragma unroll 4
    for (int i = 0; i < 32; ++i) {
        const int p = w * 32 + i;
        const int cl = sidx[p] - clo;            // wave-uniform
        if ((unsigned)cl < 256u) {
            const float x = Xh[p * DD];          // 256B coalesced per wave
            atomicAdd(&lds[cl * 64 + lane], x);  // LDS ds_add_f32
        }
    }
    __syncthreads();

    // writeout 256x64 tile -> part[g][clo+cl][h*64 + d]  (4096 float4, 16/thread)
    const float4* ls = (const float4*)lds;
    float* pg = part + (size_t)g * (KC * DD);
    #pragma unroll
    for (int r = 0; r < 16; ++r) {
        const int j  = r * 256 + t;              // 0..4095
        const int cl = j >> 4;
        const int dq = j & 15;
        *(float4*)&pg[(clo + cl) * DD + h * 64 + dq * 4] = ls[j];
    }
}

// ---------------- reduce: out[c][:] = sum_g part[g][c][:], + nItems ----------------
// 512 blocks x 128 thr. Fixed ascending-g order (deterministic); 64 independent
// loads per thread (MLP via unroll); 16 MB total read, pure BW.
__global__ __launch_bounds__(128) void kreduce2(const float* __restrict__ part,
                                                const int* __restrict__ cnts2,
                                                float* __restrict__ out) {
    const int c = blockIdx.x;
    const int d = threadIdx.x;
    const float* pc = part + (size_t)c * DD + d;
    float s = 0.f;
    #pragma unroll 8
    for (int g = 0; g < 64; ++g) s += pc[(size_t)g * (KC * DD)];
    out[c * DD + d] = s;

    if (d < 64) {
        int v = cnts2[c * 64 + d];               // coalesced 256B
        #pragma unroll
        for (int off = 32; off > 0; off >>= 1) v += __shfl_xor(v, off);
        if (d == 0) out[KC * DD + c] = (float)v;
    }
}

extern "C" void kernel_launch(void* const* d_in, const int* in_sizes, int n_in,
                              void* d_out, int out_size, void* d_ws, size_t ws_size,
                              hipStream_t stream) {
    const float* locF = (const float*)d_in[0];
    const float* Ck   = (const float*)d_in[1];
    float* out   = (float*)d_out;
    char*  ws    = (char*)d_ws;
    float* sumc2 = (float*)(ws);
    float* CkT   = (float*)(ws + 4096);
    int*   idx   = (int*)(ws + 266240);
    int*   cnts2 = (int*)(ws + 299008);
    float* part  = (float*)(ws + 430080);

    hipLaunchKernelGGL(kprep,    dim3(81),   dim3(256), 0, stream, Ck, CkT, sumc2, cnts2);
    hipLaunchKernelGGL(kassign,  dim3(1024), dim3(128), 0, stream, locF, CkT, sumc2, idx, cnts2);
    hipLaunchKernelGGL(khist,    dim3(256),  dim3(256), 0, stream, locF, idx, part);
    hipLaunchKernelGGL(kreduce2, dim3(512),  dim3(128), 0, stream, part, cnts2, out);
}